// Round 7
// baseline (162.444 us; speedup 1.0000x reference)
//
#include <hip/hip_runtime.h>
#include <stdint.h>

#define NBOX 8000
#define NPAD 8192

// ---- workspace layout (bytes) ----
#define DONE_OFF 64                          // 9 x u32: [0]=group-done, [1..8]=per-group counters
#define SB(i)    (0x10000 + (size_t)(i) * 0x8000)
// sorted-by-rank arrays (float[8192] each):
// 0 bx, 1 by, 2 bw, 3 bh, 4 conf, 5 cls, 6 x1, 7 y1, 8 x2, 9 y2, 10 area
#define NZ_OFF   (size_t)0x100000            // 8192 x 2 u64 nonzero-word bitmap (zeroed by K1)
#define M_OFF    (size_t)0x200000            // 8192 x 128 u64 suppression bit-matrix (gated by nz)

__device__ __forceinline__ float sigmoidf_(float x) {
    return 1.0f / (1.0f + expf(-x));
}

// ================= K1: fused decode-conf + ballot-rank + scatter-to-sorted =================
// (verbatim verified rounds 1-6; zeroing now covers done tree + nz bitmap)
__global__ __launch_bounds__(512) void sort_decode_kernel(const float* __restrict__ x,
                                                          const float* __restrict__ anchors,
                                                          unsigned char* __restrict__ ws) {
    __shared__ unsigned long long keys[NPAD];    // 64 KB
    __shared__ int partial[256];                 // 8 waves x 32 rows
    int tid  = threadIdx.x;
    int lane = tid & 63;
    int wv   = tid >> 6;                         // wave 0..7
    int b    = blockIdx.x;                       // 256 blocks

    if (b == 0 && tid < 16) ((unsigned int*)(ws + DONE_OFF))[tid] = 0u;
    if (tid < 64)                                // 256 blocks x 64 u64 = full 128 KB nz clear
        ((unsigned long long*)(ws + NZ_OFF))[(b << 6) + tid] = 0ull;

    // ---- phase 1: all keys -> LDS (16 coalesced loads/thread) ----
    for (int t = tid; t < NPAD; t += 512) {
        unsigned long long k;
        if (t < NBOX) {
            int a = t / 1600, pos = t - a * 1600;
            float c = sigmoidf_(x[a * 40000 + 4 * 1600 + pos]);
            k = ((unsigned long long)__float_as_uint(c) << 32) | (unsigned long long)(8191 - t);
        } else {
            k = (unsigned long long)(8191 - t);  // pads sort last (conf bits = 0)
        }
        keys[t] = k;
    }
    __syncthreads();

    // ---- phase 2: ballot-rank; wave wv vs segment wv ----
    unsigned long long kj[16];
    #pragma unroll
    for (int c = 0; c < 16; ++c) kj[c] = keys[(wv << 10) + (c << 6) + lane];
    unsigned long long ki = keys[(b << 5) + lane];

    int vout = 0;                                // lane L ends with partial for row L
    for (int ii = 0; ii < 32; ++ii) {
        unsigned int klo = (unsigned int)__builtin_amdgcn_readlane((int)(unsigned int)ki, ii);
        unsigned int khi = (unsigned int)__builtin_amdgcn_readlane((int)(unsigned int)(ki >> 32), ii);
        unsigned long long kib = ((unsigned long long)khi << 32) | (unsigned long long)klo;
        int c = 0;
        #pragma unroll
        for (int ch = 0; ch < 16; ++ch)
            c += __popcll(__ballot(kj[ch] > kib));
        vout = (lane == ii) ? c : vout;
    }
    if (lane < 32) partial[(wv << 5) + lane] = vout;
    __syncthreads();

    // ---- phase 3: wave 0 lanes 0..31 sum partials, decode, scatter-write ----
    if (wv == 0 && lane < 32) {
        int r = 0;
        #pragma unroll
        for (int s = 0; s < 8; ++s) r += partial[(s << 5) + lane];

        int i = (b << 5) + lane;                 // source box owned by this lane
        float bx = 0.f, by = 0.f, bw = 0.f, bh = 0.f, conf = 0.f, cls = -1.0f;
        if (i < NBOX) {                          // full decode (coalesced channel loads)
            int a = i / 1600, pos = i - a * 1600;
            int gy = pos / 40, gx = pos - gy * 40;
            const float* p = x + (size_t)a * 40000 + pos;
            float tx = sigmoidf_(p[0]);
            float ty = sigmoidf_(p[1600]);
            float tw = p[2 * 1600];
            float th = p[3 * 1600];
            conf = sigmoidf_(p[4 * 1600]);
            float best = -1.0f; int bi = 0;
            #pragma unroll
            for (int c = 0; c < 20; ++c) {       // first-max wins, matches jnp.argmax
                float v = sigmoidf_(p[(5 + c) * 1600]);
                if (v > best) { best = v; bi = c; }
            }
            float aw = anchors[a * 2 + 0];
            float ah = anchors[a * 2 + 1];
            bx = (tx + (float)gx) * 8.0f;
            by = (ty + (float)gy) * 8.0f;
            bw = expf(tw) * aw * 8.0f;
            bh = expf(th) * ah * 8.0f;
            cls = (float)bi;
        }
        {
        #pragma clang fp contract(off)
            float x1 = bx - bw / 2.0f, y1 = by - bh / 2.0f;
            float x2 = bx + bw / 2.0f, y2 = by + bh / 2.0f;
            float ar = fabsf((x2 - x1) * (y2 - y1));   // ref: recomputed from corners
            ((float*)(ws + SB(0)))[r]  = bx;  ((float*)(ws + SB(1)))[r]  = by;
            ((float*)(ws + SB(2)))[r]  = bw;  ((float*)(ws + SB(3)))[r]  = bh;
            ((float*)(ws + SB(4)))[r]  = conf; ((float*)(ws + SB(5)))[r] = cls;
            ((float*)(ws + SB(6)))[r]  = x1;  ((float*)(ws + SB(7)))[r]  = y1;
            ((float*)(ws + SB(8)))[r]  = x2;  ((float*)(ws + SB(9)))[r]  = y2;
            ((float*)(ws + SB(10)))[r] = ar;
        }
    }
}

// ================= K2: suppression bit-matrix + last-block word-push NMS + output =================
// Phase 0: every block pre-zeroes output rows of its invalid ranks.
// Phase 1: verified class-bitmask tile loop; emission is now ONE plain store
//          of the 64-bit suppression word M[i][jc] (single writer per word)
//          + one fire-and-forget global atomicOr into nz[i] — no edge list,
//          no counters, no dependent atomic chains.
// Tail (last block via 2-level done tree): NO bucketing passes. Wave 0
//          sweeps valid chunks in rank order; alive rows push whole 64-bit
//          M words into supp[] (one LDS atomic per nonzero word). vd lives
//          in registers (readlane); loop breaks at first empty chunk.
__global__ __launch_bounds__(512) void mask_nms_out_kernel(unsigned char* __restrict__ ws,
                                                           float* __restrict__ out) {
    __shared__ unsigned long long av[128];                // final alive bits
    __shared__ union {
        struct { float cst[2][7][64];
                 unsigned long long cm[2][20], vm[2]; } m;   // mask staging + class masks
        struct { unsigned long long vd[128], supp[128]; } r; // 2 KB resolve state
        struct { float obuf[2][3072]; } o;                   // 24 KB output staging
    } u;
    __shared__ int lastBlk;

    int tid  = threadIdx.x;
    int lane = tid & 63;
    int wv   = tid >> 6;
    int blk  = blockIdx.x;                                // 256 blocks

    const float* sconf = (const float*)(ws + SB(4));
    const float* sx1 = (const float*)(ws + SB(6));
    const float* sy1 = (const float*)(ws + SB(7));
    const float* sx2 = (const float*)(ws + SB(8));
    const float* sy2 = (const float*)(ws + SB(9));
    const float* sar = (const float*)(ws + SB(10));
    const float* scl = (const float*)(ws + SB(5));

    // ---------------- phase 0: pre-zero invalid-rank output rows ----------------
    if (tid < 192) {
        int r = (blk << 5) + tid / 6;
        if (r < NBOX && !(sconf[r] > 0.5f))               // NaN/poison-safe negated test
            out[r * 6 + tid % 6] = 0.0f;
    }

    // ---------------- phase 1: tiles -> suppression-matrix words ----------------
    {
    #pragma clang fp contract(off)
        int h  = tid >> 8;                       // half-block 0/1 (4 waves each)
        int tl = tid & 255;

        for (int k = 0; k < 8; ++k) {
            int t  = k * 512 + (blk << 1) + h;   // tile id in [0, 4096)
            int iy = t >> 7, w = t & 127;
            int i0 = iy << 8, j0 = w << 6;
            bool skip = (sconf[i0] <= 0.5f) || (sconf[j0] <= 0.5f) || (j0 + 64 <= i0);

            if (!skip && tl < 64) {              // full wave: stage cols + build masks
                int j = j0 + tl;
                float c0 = sx1[j], c1 = sy1[j], c2 = sx2[j], c3 = sy2[j];
                float c4 = sar[j], c5 = scl[j], c6 = sconf[j];
                u.m.cst[h][0][tl] = c0; u.m.cst[h][1][tl] = c1;
                u.m.cst[h][2][tl] = c2; u.m.cst[h][3][tl] = c3;
                u.m.cst[h][4][tl] = c4; u.m.cst[h][5][tl] = c5;
                u.m.cst[h][6][tl] = c6;
                unsigned long long vmk = __ballot(c6 > 0.5f);      // NaN-safe
                if (tl == 0) u.m.vm[h] = vmk;
                #pragma unroll
                for (int cl = 0; cl < 20; ++cl) {
                    unsigned long long mk = __ballot(c5 == (float)cl);
                    if (tl == 0) u.m.cm[h][cl] = mk;
                }
            }
            __syncthreads();

            if (!skip) {
                int i = i0 + tl;
                unsigned long long word = 0;
                if (sconf[i] > 0.5f && j0 + 64 > i + 1) {  // row i valid
                    float x1i = sx1[i], y1i = sy1[i], x2i = sx2[i], y2i = sy2[i];
                    float ai = sar[i], ci = scl[i];
                    int cii = (int)ci;
                    unsigned long long allowed = 0ull;
                    if (cii >= 0 && cii < 20)
                        allowed = u.m.cm[h][cii] & u.m.vm[h];
                    int d = i - j0 + 1;                    // first allowed col: j>i
                    unsigned long long gt =
                        (d <= 0) ? ~0ull : (d >= 64 ? 0ull : (~0ull << d));
                    unsigned long long it = allowed & gt;
                    while (it) {
                        int jj = __builtin_ctzll(it);
                        it &= it - 1ull;
                        float iw = fminf(x2i, u.m.cst[h][2][jj]) - fmaxf(x1i, u.m.cst[h][0][jj]);
                        iw = fmaxf(iw, 0.0f);
                        float ih = fminf(y2i, u.m.cst[h][3][jj]) - fmaxf(y1i, u.m.cst[h][1][jj]);
                        ih = fmaxf(ih, 0.0f);
                        float inter = iw * ih;
                        float denom = ai + u.m.cst[h][4][jj] - inter + 1e-6f;
                        if (inter / denom >= 0.5f) word |= (1ull << jj);
                    }
                }
                if (word) {                      // fire-and-forget; single writer per M word
                    int jc = j0 >> 6;
                    ((unsigned long long*)(ws + M_OFF))[(size_t)i * 128 + jc] = word;
                    atomicOr(((unsigned long long*)(ws + NZ_OFF)) + 2 * i + (jc >> 6),
                             1ull << (jc & 63));
                }
            }
            __syncthreads();
        }
    }

    // ---------------- completion: 2-level done tree (8 groups x 32 blocks) ----------------
    __threadfence();                              // release this block's M/nz writes
    if (tid == 0) {
        unsigned int* dc = (unsigned int*)(ws + DONE_OFF);
        lastBlk = 0;
        if (atomicAdd(dc + 1 + (blk & 7), 1u) == 31u)
            if (atomicAdd(dc, 1u) == 7u) lastBlk = 1;
    }
    __syncthreads();
    if (!lastBlk) return;
    __threadfence();                              // acquire: see all blocks' M/nz

    // ---------------- tail step 1: valid bitmap + zero resolve state ----------------
    for (int c = wv; c < 128; c += 8) {
        unsigned long long mk = __ballot(sconf[(c << 6) + lane] > 0.5f);
        if (lane == 0) u.r.vd[c] = mk;
    }
    if (tid < 128) { u.r.supp[tid] = 0ull; av[tid] = 0ull; }
    __syncthreads();

    // ---------------- tail step 2: word-push greedy sweep (wave 0) ----------------
    if (wv == 0) {
        unsigned long long vdlo = u.r.vd[lane];          // vd in registers
        unsigned long long vdhi = u.r.vd[64 + lane];
        const unsigned long long* Mx = (const unsigned long long*)(ws + M_OFF);
        const ulonglong2* nzv = (const ulonglong2*)(ws + NZ_OFF);

        for (int jc = 0; jc < 128; ++jc) {
            unsigned long long vsrc = (jc < 64) ? vdlo : vdhi;
            unsigned int vlo = (unsigned int)__builtin_amdgcn_readlane((int)(unsigned int)vsrc, jc & 63);
            unsigned int vhi = (unsigned int)__builtin_amdgcn_readlane((int)(unsigned int)(vsrc >> 32), jc & 63);
            unsigned long long v = ((unsigned long long)vhi << 32) | (unsigned long long)vlo;
            if (v == 0ull) break;                 // sorted: no valid boxes beyond

            int i = (jc << 6) + lane;             // lane <-> row of this chunk
            ulonglong2 nzp = nzv[i];              // coalesced 16B/lane
            unsigned long long nz0 = nzp.x, nz1 = nzp.y;
            unsigned long long nzc = (jc < 64) ? nz0 : nz1;
            unsigned long long diag = 0ull;
            if ((nzc >> (jc & 63)) & 1ull)        // rare: intra-chunk word exists
                diag = Mx[(size_t)i * 128 + jc];

            unsigned long long sj = u.r.supp[jc]; // all pushes into jc already drained
            unsigned long long a = v & ~sj;

            // intra-chunk: ascending scan over rows with intra bits (bits j>i only)
            unsigned long long scan = __ballot(diag != 0ull) & a;
            while (scan) {
                int ib = __builtin_ctzll(scan);
                scan &= scan - 1ull;
                if ((a >> ib) & 1ull) {
                    unsigned int dlo = (unsigned int)__builtin_amdgcn_readlane((int)(unsigned int)diag, ib);
                    unsigned int dhi = (unsigned int)__builtin_amdgcn_readlane((int)(unsigned int)(diag >> 32), ib);
                    a &= ~(((unsigned long long)dhi << 32) | (unsigned long long)dlo);
                }
            }
            if (lane == 0) av[jc] = a;

            // push: alive rows OR their nonzero M words into future chunks' supp
            if ((a >> lane) & 1ull) {
                unsigned long long c0 = nz0, c1 = nz1;
                if (jc < 64) c0 &= ~(1ull << jc); else c1 &= ~(1ull << (jc & 63));
                while (c0) {
                    int w = __builtin_ctzll(c0); c0 &= c0 - 1ull;
                    atomicOr(&u.r.supp[w], Mx[(size_t)i * 128 + w]);
                }
                while (c1) {
                    int w = __builtin_ctzll(c1); c1 &= c1 - 1ull;
                    atomicOr(&u.r.supp[64 + w], Mx[(size_t)i * 128 + 64 + w]);
                }
            }
            asm volatile("s_waitcnt vmcnt(0) lgkmcnt(0)" ::: "memory");  // pushes visible
            __builtin_amdgcn_sched_barrier(0);
        }
    }
    __syncthreads();

    // ---------------- output: only chunks containing valid ranks (rest pre-zeroed) ----------------
    {
        const float* s0 = (const float*)(ws + SB(0));
        const float* s1 = (const float*)(ws + SB(1));
        const float* s2 = (const float*)(ws + SB(2));
        const float* s3 = (const float*)(ws + SB(3));
        const float* s4 = (const float*)(ws + SB(4));
        const float* s5 = (const float*)(ws + SB(5));

        for (int c = 0; c < 16; ++c) {
            if (!(sconf[c << 9] > 0.5f)) continue;   // sorted: chunk fully invalid (uniform)
            int r = (c << 9) + tid;               // rank 0..8191
            int p = c & 1;
            float v0 = 0.f, v1 = 0.f, v2 = 0.f, v3 = 0.f, v4 = 0.f, v5 = 0.f;
            if ((av[r >> 6] >> (r & 63)) & 1ull) {
                v0 = s0[r]; v1 = s1[r]; v2 = s2[r];
                v3 = s3[r]; v4 = s4[r]; v5 = s5[r];
            }
            u.o.obuf[p][tid * 6 + 0] = v0; u.o.obuf[p][tid * 6 + 1] = v1;
            u.o.obuf[p][tid * 6 + 2] = v2; u.o.obuf[p][tid * 6 + 3] = v3;
            u.o.obuf[p][tid * 6 + 4] = v4; u.o.obuf[p][tid * 6 + 5] = v5;
            __syncthreads();
            int basef = c * 3072;                 // float index of chunk start
            const float4* src = (const float4*)u.o.obuf[p];
            float4* dst = (float4*)(out + basef);
            #pragma unroll
            for (int tq = tid; tq < 768; tq += 512)
                if ((basef >> 2) + tq < (NBOX * 6) / 4) dst[tq] = src[tq];
        }
    }
}

extern "C" void kernel_launch(void* const* d_in, const int* in_sizes, int n_in,
                              void* d_out, int out_size, void* d_ws, size_t ws_size,
                              hipStream_t stream) {
    const float* x       = (const float*)d_in[0];
    const float* anchors = (const float*)d_in[1];
    float* out           = (float*)d_out;
    unsigned char* ws    = (unsigned char*)d_ws;

    sort_decode_kernel<<<256, 512, 0, stream>>>(x, anchors, ws);
    mask_nms_out_kernel<<<256, 512, 0, stream>>>(ws, out);
}

// Round 8
// 159.334 us; speedup vs baseline: 1.0195x; 1.0195x over previous
//
#include <hip/hip_runtime.h>
#include <stdint.h>

#define NBOX 8000
#define NPAD 8192
#define CAP2 4096                            // packed cross-word LDS capacity

// ---- workspace layout (bytes) ----
#define DONE_OFF 64                          // 9 x u32: [0]=group-done, [1..8]=per-group counters
#define SB(i)    (0x10000 + (size_t)(i) * 0x8000)
// sorted-by-rank arrays (float[8192] each):
// 0 bx, 1 by, 2 bw, 3 bh, 4 conf, 5 cls, 6 x1, 7 y1, 8 x2, 9 y2, 10 area
#define NZ_OFF   (size_t)0x100000            // 8192 x 2 u64 nonzero-word bitmap (zeroed by K1)
#define M_OFF    (size_t)0x200000            // 8192 x 128 u64 suppression bit-matrix (gated by nz)

__device__ __forceinline__ float sigmoidf_(float x) {
    return 1.0f / (1.0f + expf(-x));
}

// ================= K1: fused decode-conf + ballot-rank + scatter-to-sorted =================
// (verbatim verified rounds 1-7)
__global__ __launch_bounds__(512) void sort_decode_kernel(const float* __restrict__ x,
                                                          const float* __restrict__ anchors,
                                                          unsigned char* __restrict__ ws) {
    __shared__ unsigned long long keys[NPAD];    // 64 KB
    __shared__ int partial[256];                 // 8 waves x 32 rows
    int tid  = threadIdx.x;
    int lane = tid & 63;
    int wv   = tid >> 6;                         // wave 0..7
    int b    = blockIdx.x;                       // 256 blocks

    if (b == 0 && tid < 16) ((unsigned int*)(ws + DONE_OFF))[tid] = 0u;
    if (tid < 64)                                // 256 blocks x 64 u64 = full 128 KB nz clear
        ((unsigned long long*)(ws + NZ_OFF))[(b << 6) + tid] = 0ull;

    // ---- phase 1: all keys -> LDS (16 coalesced loads/thread) ----
    for (int t = tid; t < NPAD; t += 512) {
        unsigned long long k;
        if (t < NBOX) {
            int a = t / 1600, pos = t - a * 1600;
            float c = sigmoidf_(x[a * 40000 + 4 * 1600 + pos]);
            k = ((unsigned long long)__float_as_uint(c) << 32) | (unsigned long long)(8191 - t);
        } else {
            k = (unsigned long long)(8191 - t);  // pads sort last (conf bits = 0)
        }
        keys[t] = k;
    }
    __syncthreads();

    // ---- phase 2: ballot-rank; wave wv vs segment wv ----
    unsigned long long kj[16];
    #pragma unroll
    for (int c = 0; c < 16; ++c) kj[c] = keys[(wv << 10) + (c << 6) + lane];
    unsigned long long ki = keys[(b << 5) + lane];

    int vout = 0;                                // lane L ends with partial for row L
    for (int ii = 0; ii < 32; ++ii) {
        unsigned int klo = (unsigned int)__builtin_amdgcn_readlane((int)(unsigned int)ki, ii);
        unsigned int khi = (unsigned int)__builtin_amdgcn_readlane((int)(unsigned int)(ki >> 32), ii);
        unsigned long long kib = ((unsigned long long)khi << 32) | (unsigned long long)klo;
        int c = 0;
        #pragma unroll
        for (int ch = 0; ch < 16; ++ch)
            c += __popcll(__ballot(kj[ch] > kib));
        vout = (lane == ii) ? c : vout;
    }
    if (lane < 32) partial[(wv << 5) + lane] = vout;
    __syncthreads();

    // ---- phase 3: wave 0 lanes 0..31 sum partials, decode, scatter-write ----
    if (wv == 0 && lane < 32) {
        int r = 0;
        #pragma unroll
        for (int s = 0; s < 8; ++s) r += partial[(s << 5) + lane];

        int i = (b << 5) + lane;                 // source box owned by this lane
        float bx = 0.f, by = 0.f, bw = 0.f, bh = 0.f, conf = 0.f, cls = -1.0f;
        if (i < NBOX) {                          // full decode (coalesced channel loads)
            int a = i / 1600, pos = i - a * 1600;
            int gy = pos / 40, gx = pos - gy * 40;
            const float* p = x + (size_t)a * 40000 + pos;
            float tx = sigmoidf_(p[0]);
            float ty = sigmoidf_(p[1600]);
            float tw = p[2 * 1600];
            float th = p[3 * 1600];
            conf = sigmoidf_(p[4 * 1600]);
            float best = -1.0f; int bi = 0;
            #pragma unroll
            for (int c = 0; c < 20; ++c) {       // first-max wins, matches jnp.argmax
                float v = sigmoidf_(p[(5 + c) * 1600]);
                if (v > best) { best = v; bi = c; }
            }
            float aw = anchors[a * 2 + 0];
            float ah = anchors[a * 2 + 1];
            bx = (tx + (float)gx) * 8.0f;
            by = (ty + (float)gy) * 8.0f;
            bw = expf(tw) * aw * 8.0f;
            bh = expf(th) * ah * 8.0f;
            cls = (float)bi;
        }
        {
        #pragma clang fp contract(off)
            float x1 = bx - bw / 2.0f, y1 = by - bh / 2.0f;
            float x2 = bx + bw / 2.0f, y2 = by + bh / 2.0f;
            float ar = fabsf((x2 - x1) * (y2 - y1));   // ref: recomputed from corners
            ((float*)(ws + SB(0)))[r]  = bx;  ((float*)(ws + SB(1)))[r]  = by;
            ((float*)(ws + SB(2)))[r]  = bw;  ((float*)(ws + SB(3)))[r]  = bh;
            ((float*)(ws + SB(4)))[r]  = conf; ((float*)(ws + SB(5)))[r] = cls;
            ((float*)(ws + SB(6)))[r]  = x1;  ((float*)(ws + SB(7)))[r]  = y1;
            ((float*)(ws + SB(8)))[r]  = x2;  ((float*)(ws + SB(9)))[r]  = y2;
            ((float*)(ws + SB(10)))[r] = ar;
        }
    }
}

// ================= K2: suppression bit-matrix + last-block LDS-staged push NMS + output =================
// Phase 1 (grid): verified class-bitmask tile loop; emits 64-bit suppression
//          words M[i][jc] (plain store, single writer) + nz[i] directory bit.
// Tail (last block): stage via the nz directory — NO atomic storms (round 6's
//          41.7K-conflict bucketing) and NO global loads inside the sweep's
//          dependent chain (round 7's regression). Intra words -> direct-
//          mapped LDS (plain stores); cross words -> packed per-chunk LDS
//          lists via wave prefix-scans. Sweep = verified r7 word-push over
//          LDS only. Global fallback path (verified r7) if CAP2 overflows.
__global__ __launch_bounds__(512) void mask_nms_out_kernel(unsigned char* __restrict__ ws,
                                                           float* __restrict__ out) {
    __shared__ unsigned long long av[128];                // final alive bits
    __shared__ union {
        struct { float cst[2][7][64];
                 unsigned long long cm[2][20], vm[2]; } m;   // mask staging + class masks
        struct { unsigned long long vd[128], supp[128];      // 2 KB
                 unsigned long long intra[128 * 64];         // 64 KB direct-mapped intra words
                 unsigned long long eword[CAP2];             // 32 KB packed cross words
                 unsigned short emeta[CAP2];                 // 8 KB  (row<<7)|target
                 unsigned int ccnt[128], offs[128];
                 unsigned int tot; } r;                      // ~107 KB resolve staging
        struct { float obuf[2][3072]; } o;                   // 24 KB output staging
    } u;
    __shared__ int lastBlk;

    int tid  = threadIdx.x;
    int lane = tid & 63;
    int wv   = tid >> 6;
    int blk  = blockIdx.x;                                // 256 blocks

    const float* sconf = (const float*)(ws + SB(4));
    const float* sx1 = (const float*)(ws + SB(6));
    const float* sy1 = (const float*)(ws + SB(7));
    const float* sx2 = (const float*)(ws + SB(8));
    const float* sy2 = (const float*)(ws + SB(9));
    const float* sar = (const float*)(ws + SB(10));
    const float* scl = (const float*)(ws + SB(5));

    // ---------------- phase 0: pre-zero invalid-rank output rows ----------------
    if (tid < 192) {
        int r = (blk << 5) + tid / 6;
        if (r < NBOX && !(sconf[r] > 0.5f))               // NaN/poison-safe negated test
            out[r * 6 + tid % 6] = 0.0f;
    }

    // ---------------- phase 1: tiles -> suppression-matrix words (verified r7) ----------------
    {
    #pragma clang fp contract(off)
        int h  = tid >> 8;                       // half-block 0/1 (4 waves each)
        int tl = tid & 255;

        for (int k = 0; k < 8; ++k) {
            int t  = k * 512 + (blk << 1) + h;   // tile id in [0, 4096)
            int iy = t >> 7, w = t & 127;
            int i0 = iy << 8, j0 = w << 6;
            bool skip = (sconf[i0] <= 0.5f) || (sconf[j0] <= 0.5f) || (j0 + 64 <= i0);

            if (!skip && tl < 64) {              // full wave: stage cols + build masks
                int j = j0 + tl;
                float c0 = sx1[j], c1 = sy1[j], c2 = sx2[j], c3 = sy2[j];
                float c4 = sar[j], c5 = scl[j], c6 = sconf[j];
                u.m.cst[h][0][tl] = c0; u.m.cst[h][1][tl] = c1;
                u.m.cst[h][2][tl] = c2; u.m.cst[h][3][tl] = c3;
                u.m.cst[h][4][tl] = c4; u.m.cst[h][5][tl] = c5;
                u.m.cst[h][6][tl] = c6;
                unsigned long long vmk = __ballot(c6 > 0.5f);      // NaN-safe
                if (tl == 0) u.m.vm[h] = vmk;
                #pragma unroll
                for (int cl = 0; cl < 20; ++cl) {
                    unsigned long long mk = __ballot(c5 == (float)cl);
                    if (tl == 0) u.m.cm[h][cl] = mk;
                }
            }
            __syncthreads();

            if (!skip) {
                int i = i0 + tl;
                unsigned long long word = 0;
                if (sconf[i] > 0.5f && j0 + 64 > i + 1) {  // row i valid
                    float x1i = sx1[i], y1i = sy1[i], x2i = sx2[i], y2i = sy2[i];
                    float ai = sar[i], ci = scl[i];
                    int cii = (int)ci;
                    unsigned long long allowed = 0ull;
                    if (cii >= 0 && cii < 20)
                        allowed = u.m.cm[h][cii] & u.m.vm[h];
                    int d = i - j0 + 1;                    // first allowed col: j>i
                    unsigned long long gt =
                        (d <= 0) ? ~0ull : (d >= 64 ? 0ull : (~0ull << d));
                    unsigned long long it = allowed & gt;
                    while (it) {
                        int jj = __builtin_ctzll(it);
                        it &= it - 1ull;
                        float iw = fminf(x2i, u.m.cst[h][2][jj]) - fmaxf(x1i, u.m.cst[h][0][jj]);
                        iw = fmaxf(iw, 0.0f);
                        float ih = fminf(y2i, u.m.cst[h][3][jj]) - fmaxf(y1i, u.m.cst[h][1][jj]);
                        ih = fmaxf(ih, 0.0f);
                        float inter = iw * ih;
                        float denom = ai + u.m.cst[h][4][jj] - inter + 1e-6f;
                        if (inter / denom >= 0.5f) word |= (1ull << jj);
                    }
                }
                if (word) {                      // fire-and-forget; single writer per M word
                    int jc = j0 >> 6;
                    ((unsigned long long*)(ws + M_OFF))[(size_t)i * 128 + jc] = word;
                    atomicOr(((unsigned long long*)(ws + NZ_OFF)) + 2 * i + (jc >> 6),
                             1ull << (jc & 63));
                }
            }
            __syncthreads();
        }
    }

    // ---------------- completion: 2-level done tree (verified r7) ----------------
    __threadfence();                              // release this block's M/nz writes
    if (tid == 0) {
        unsigned int* dc = (unsigned int*)(ws + DONE_OFF);
        lastBlk = 0;
        if (atomicAdd(dc + 1 + (blk & 7), 1u) == 31u)
            if (atomicAdd(dc, 1u) == 7u) lastBlk = 1;
    }
    __syncthreads();
    if (!lastBlk) return;
    __threadfence();                              // acquire: see all blocks' M/nz

    const unsigned long long* Mx = (const unsigned long long*)(ws + M_OFF);
    const ulonglong2* nzv = (const ulonglong2*)(ws + NZ_OFF);

    // ---------------- tail step 1: valid bitmap + zero resolve state ----------------
    for (int c = wv; c < 128; c += 8) {
        unsigned long long mk = __ballot(sconf[(c << 6) + lane] > 0.5f);
        if (lane == 0) u.r.vd[c] = mk;
    }
    for (int t = tid; t < 128 * 64; t += 512) u.r.intra[t] = 0ull;
    if (tid < 128) { u.r.supp[tid] = 0ull; av[tid] = 0ull; }
    __syncthreads();

    // ---------------- tail step 2a: per-chunk cross counts + intra staging ----------------
    for (int c = wv; c < 128; c += 8) {           // lane <-> row of chunk c
        int i = (c << 6) + lane;
        ulonglong2 nzp = nzv[i];                  // coalesced 16B/lane
        unsigned long long c0 = nzp.x, c1 = nzp.y;
        int cb = c & 63;
        if (c < 64) {
            if ((c0 >> cb) & 1ull) u.r.intra[(c << 6) + lane] = Mx[(size_t)i * 128 + c];
            c0 &= ~(1ull << cb);
        } else {
            if ((c1 >> cb) & 1ull) u.r.intra[(c << 6) + lane] = Mx[(size_t)i * 128 + c];
            c1 &= ~(1ull << cb);
        }
        int pc = __popcll(c0) + __popcll(c1);
        int scan = pc;
        #pragma unroll
        for (int d = 1; d < 64; d <<= 1) {
            int t = __shfl_up(scan, d, 64);
            if (lane >= d) scan += t;
        }
        if (lane == 63) u.r.ccnt[c] = (unsigned int)scan;
    }
    __syncthreads();

    // ---------------- tail step 2b: 128-entry exclusive scan (wave 0, verified) ----------------
    if (wv == 0) {
        unsigned int a0 = u.r.ccnt[2 * lane + 0];
        unsigned int a1 = u.r.ccnt[2 * lane + 1];
        unsigned int s = a0 + a1, incl = s;
        #pragma unroll
        for (int d = 1; d < 64; d <<= 1) {
            unsigned int t = __shfl_up(incl, d, 64);
            if (lane >= d) incl += t;
        }
        unsigned int excl = incl - s;
        u.r.offs[2 * lane + 0] = excl;  u.r.offs[2 * lane + 1] = excl + a0;
        if (lane == 63) u.r.tot = incl;
    }
    __syncthreads();
    bool fits = (u.r.tot <= (unsigned int)CAP2);

    // ---------------- tail step 2c: pack cross words into LDS ----------------
    if (fits) {
        for (int c = wv; c < 128; c += 8) {
            int i = (c << 6) + lane;
            ulonglong2 nzp = nzv[i];              // L2-hot re-read
            unsigned long long c0 = nzp.x, c1 = nzp.y;
            int cb = c & 63;
            if (c < 64) c0 &= ~(1ull << cb); else c1 &= ~(1ull << cb);
            int pc = __popcll(c0) + __popcll(c1);
            int scan = pc;
            #pragma unroll
            for (int d = 1; d < 64; d <<= 1) {
                int t = __shfl_up(scan, d, 64);
                if (lane >= d) scan += t;
            }
            unsigned int o = u.r.offs[c] + (unsigned int)(scan - pc);
            while (c0) {
                int w = __builtin_ctzll(c0); c0 &= c0 - 1ull;
                u.r.emeta[o] = (unsigned short)((lane << 7) | w);
                u.r.eword[o] = Mx[(size_t)i * 128 + w];
                ++o;
            }
            while (c1) {
                int w = 64 + __builtin_ctzll(c1); c1 &= c1 - 1ull;
                u.r.emeta[o] = (unsigned short)((lane << 7) | w);
                u.r.eword[o] = Mx[(size_t)i * 128 + w];
                ++o;
            }
        }
    }
    __syncthreads();

    // ---------------- tail step 3: LDS word-push greedy sweep (wave 0, verified r7 semantics) ----------------
    if (wv == 0) {
        unsigned long long vdlo = u.r.vd[lane];          // vd in registers
        unsigned long long vdhi = u.r.vd[64 + lane];

        for (int jc = 0; jc < 128; ++jc) {
            unsigned long long vsrc = (jc < 64) ? vdlo : vdhi;
            unsigned int vlo = (unsigned int)__builtin_amdgcn_readlane((int)(unsigned int)vsrc, jc & 63);
            unsigned int vhi = (unsigned int)__builtin_amdgcn_readlane((int)(unsigned int)(vsrc >> 32), jc & 63);
            unsigned long long v = ((unsigned long long)vhi << 32) | (unsigned long long)vlo;
            if (v == 0ull) break;                 // sorted: no valid boxes beyond

            unsigned long long sj = u.r.supp[jc]; // pushes into jc already drained
            unsigned long long a = v & ~sj;

            // intra-chunk: ascending scan over rows with intra bits (bits j>i only)
            unsigned long long diag = u.r.intra[(jc << 6) + lane];
            unsigned long long scan = __ballot(diag != 0ull) & a;
            while (scan) {
                int ib = __builtin_ctzll(scan);
                scan &= scan - 1ull;
                if ((a >> ib) & 1ull) {
                    unsigned int dlo = (unsigned int)__builtin_amdgcn_readlane((int)(unsigned int)diag, ib);
                    unsigned int dhi = (unsigned int)__builtin_amdgcn_readlane((int)(unsigned int)(diag >> 32), ib);
                    a &= ~(((unsigned long long)dhi << 32) | (unsigned long long)dlo);
                }
            }
            if (lane == 0) av[jc] = a;

            if (fits) {
                // push packed cross words of alive rows (LDS only)
                unsigned int cnt = u.r.ccnt[jc], base = u.r.offs[jc];
                for (unsigned int e0 = 0; e0 < cnt; e0 += 64) {
                    unsigned int e = e0 + lane;
                    if (e < cnt) {
                        unsigned int m = u.r.emeta[base + e];
                        if ((a >> (m >> 7)) & 1ull)
                            atomicOr(&u.r.supp[m & 127], u.r.eword[base + e]);
                    }
                }
            } else {
                // fallback: push from global M (verified r7 path; E overflow only)
                int i = (jc << 6) + lane;
                ulonglong2 nzp = nzv[i];
                unsigned long long c0 = nzp.x, c1 = nzp.y;
                if (jc < 64) c0 &= ~(1ull << jc); else c1 &= ~(1ull << (jc & 63));
                if ((a >> lane) & 1ull) {
                    while (c0) {
                        int w = __builtin_ctzll(c0); c0 &= c0 - 1ull;
                        atomicOr(&u.r.supp[w], Mx[(size_t)i * 128 + w]);
                    }
                    while (c1) {
                        int w = __builtin_ctzll(c1); c1 &= c1 - 1ull;
                        atomicOr(&u.r.supp[64 + w], Mx[(size_t)i * 128 + 64 + w]);
                    }
                }
                asm volatile("s_waitcnt vmcnt(0)" ::: "memory");
            }
            asm volatile("s_waitcnt lgkmcnt(0)" ::: "memory");  // pushes visible
            __builtin_amdgcn_sched_barrier(0);
        }
    }
    __syncthreads();

    // ---------------- output: only chunks containing valid ranks (rest pre-zeroed) ----------------
    {
        const float* s0 = (const float*)(ws + SB(0));
        const float* s1 = (const float*)(ws + SB(1));
        const float* s2 = (const float*)(ws + SB(2));
        const float* s3 = (const float*)(ws + SB(3));
        const float* s4 = (const float*)(ws + SB(4));
        const float* s5 = (const float*)(ws + SB(5));

        for (int c = 0; c < 16; ++c) {
            if (!(sconf[c << 9] > 0.5f)) continue;   // sorted: chunk fully invalid (uniform)
            int r = (c << 9) + tid;               // rank 0..8191
            int p = c & 1;
            float v0 = 0.f, v1 = 0.f, v2 = 0.f, v3 = 0.f, v4 = 0.f, v5 = 0.f;
            if ((av[r >> 6] >> (r & 63)) & 1ull) {
                v0 = s0[r]; v1 = s1[r]; v2 = s2[r];
                v3 = s3[r]; v4 = s4[r]; v5 = s5[r];
            }
            u.o.obuf[p][tid * 6 + 0] = v0; u.o.obuf[p][tid * 6 + 1] = v1;
            u.o.obuf[p][tid * 6 + 2] = v2; u.o.obuf[p][tid * 6 + 3] = v3;
            u.o.obuf[p][tid * 6 + 4] = v4; u.o.obuf[p][tid * 6 + 5] = v5;
            __syncthreads();
            int basef = c * 3072;                 // float index of chunk start
            const float4* src = (const float4*)u.o.obuf[p];
            float4* dst = (float4*)(out + basef);
            #pragma unroll
            for (int tq = tid; tq < 768; tq += 512)
                if ((basef >> 2) + tq < (NBOX * 6) / 4) dst[tq] = src[tq];
        }
    }
}

extern "C" void kernel_launch(void* const* d_in, const int* in_sizes, int n_in,
                              void* d_out, int out_size, void* d_ws, size_t ws_size,
                              hipStream_t stream) {
    const float* x       = (const float*)d_in[0];
    const float* anchors = (const float*)d_in[1];
    float* out           = (float*)d_out;
    unsigned char* ws    = (unsigned char*)d_ws;

    sort_decode_kernel<<<256, 512, 0, stream>>>(x, anchors, ws);
    mask_nms_out_kernel<<<256, 512, 0, stream>>>(ws, out);
}

// Round 9
// 153.678 us; speedup vs baseline: 1.0570x; 1.0368x over previous
//
#include <hip/hip_runtime.h>
#include <stdint.h>

#define NBOX 8000
#define NPAD 8192
#define CAP2 4096                            // packed cross-word LDS capacity

// ---- workspace layout (bytes) ----
#define DONE_OFF 64                          // 9 x u32: [0]=group-done, [1..8]=per-group counters
#define SB(i)    (0x10000 + (size_t)(i) * 0x8000)
// sorted-by-rank arrays (float[8192] each):
// 0 bx, 1 by, 2 bw, 3 bh, 4 conf, 5 cls, 6 x1, 7 y1, 8 x2, 9 y2, 10 area
#define NZ_OFF   (size_t)0x100000            // 8192 x 2 u64 nonzero-word bitmap (zeroed by K1)
#define M_OFF    (size_t)0x200000            // 8192 x 128 u64 suppression bit-matrix (gated by nz)

__device__ __forceinline__ float sigmoidf_(float x) {
    return 1.0f / (1.0f + expf(-x));
}

// ================= K1: fused decode-conf + ballot-rank + scatter-to-sorted =================
// (verbatim verified rounds 1-8)
__global__ __launch_bounds__(512) void sort_decode_kernel(const float* __restrict__ x,
                                                          const float* __restrict__ anchors,
                                                          unsigned char* __restrict__ ws) {
    __shared__ unsigned long long keys[NPAD];    // 64 KB
    __shared__ int partial[256];                 // 8 waves x 32 rows
    int tid  = threadIdx.x;
    int lane = tid & 63;
    int wv   = tid >> 6;                         // wave 0..7
    int b    = blockIdx.x;                       // 256 blocks

    if (b == 0 && tid < 16) ((unsigned int*)(ws + DONE_OFF))[tid] = 0u;
    if (tid < 64)                                // 256 blocks x 64 u64 = full 128 KB nz clear
        ((unsigned long long*)(ws + NZ_OFF))[(b << 6) + tid] = 0ull;

    // ---- phase 1: all keys -> LDS (16 coalesced loads/thread) ----
    for (int t = tid; t < NPAD; t += 512) {
        unsigned long long k;
        if (t < NBOX) {
            int a = t / 1600, pos = t - a * 1600;
            float c = sigmoidf_(x[a * 40000 + 4 * 1600 + pos]);
            k = ((unsigned long long)__float_as_uint(c) << 32) | (unsigned long long)(8191 - t);
        } else {
            k = (unsigned long long)(8191 - t);  // pads sort last (conf bits = 0)
        }
        keys[t] = k;
    }
    __syncthreads();

    // ---- phase 2: ballot-rank; wave wv vs segment wv ----
    unsigned long long kj[16];
    #pragma unroll
    for (int c = 0; c < 16; ++c) kj[c] = keys[(wv << 10) + (c << 6) + lane];
    unsigned long long ki = keys[(b << 5) + lane];

    int vout = 0;                                // lane L ends with partial for row L
    for (int ii = 0; ii < 32; ++ii) {
        unsigned int klo = (unsigned int)__builtin_amdgcn_readlane((int)(unsigned int)ki, ii);
        unsigned int khi = (unsigned int)__builtin_amdgcn_readlane((int)(unsigned int)(ki >> 32), ii);
        unsigned long long kib = ((unsigned long long)khi << 32) | (unsigned long long)klo;
        int c = 0;
        #pragma unroll
        for (int ch = 0; ch < 16; ++ch)
            c += __popcll(__ballot(kj[ch] > kib));
        vout = (lane == ii) ? c : vout;
    }
    if (lane < 32) partial[(wv << 5) + lane] = vout;
    __syncthreads();

    // ---- phase 3: wave 0 lanes 0..31 sum partials, decode, scatter-write ----
    if (wv == 0 && lane < 32) {
        int r = 0;
        #pragma unroll
        for (int s = 0; s < 8; ++s) r += partial[(s << 5) + lane];

        int i = (b << 5) + lane;                 // source box owned by this lane
        float bx = 0.f, by = 0.f, bw = 0.f, bh = 0.f, conf = 0.f, cls = -1.0f;
        if (i < NBOX) {                          // full decode (coalesced channel loads)
            int a = i / 1600, pos = i - a * 1600;
            int gy = pos / 40, gx = pos - gy * 40;
            const float* p = x + (size_t)a * 40000 + pos;
            float tx = sigmoidf_(p[0]);
            float ty = sigmoidf_(p[1600]);
            float tw = p[2 * 1600];
            float th = p[3 * 1600];
            conf = sigmoidf_(p[4 * 1600]);
            float best = -1.0f; int bi = 0;
            #pragma unroll
            for (int c = 0; c < 20; ++c) {       // first-max wins, matches jnp.argmax
                float v = sigmoidf_(p[(5 + c) * 1600]);
                if (v > best) { best = v; bi = c; }
            }
            float aw = anchors[a * 2 + 0];
            float ah = anchors[a * 2 + 1];
            bx = (tx + (float)gx) * 8.0f;
            by = (ty + (float)gy) * 8.0f;
            bw = expf(tw) * aw * 8.0f;
            bh = expf(th) * ah * 8.0f;
            cls = (float)bi;
        }
        {
        #pragma clang fp contract(off)
            float x1 = bx - bw / 2.0f, y1 = by - bh / 2.0f;
            float x2 = bx + bw / 2.0f, y2 = by + bh / 2.0f;
            float ar = fabsf((x2 - x1) * (y2 - y1));   // ref: recomputed from corners
            ((float*)(ws + SB(0)))[r]  = bx;  ((float*)(ws + SB(1)))[r]  = by;
            ((float*)(ws + SB(2)))[r]  = bw;  ((float*)(ws + SB(3)))[r]  = bh;
            ((float*)(ws + SB(4)))[r]  = conf; ((float*)(ws + SB(5)))[r] = cls;
            ((float*)(ws + SB(6)))[r]  = x1;  ((float*)(ws + SB(7)))[r]  = y1;
            ((float*)(ws + SB(8)))[r]  = x2;  ((float*)(ws + SB(9)))[r]  = y2;
            ((float*)(ws + SB(10)))[r] = ar;
        }
    }
}

// ================= K2: suppression bit-matrix + last-block pipelined NMS/output =================
// Grid phase: verified class-bitmask tile loop; emits M[i][jc] words + nz bits.
// Tail (last block): stage intra/cross words in LDS (nz cached in registers
// across the two passes), then DIVERGE:
//   wave 0   = word-push greedy sweep (verified r7/r8 semantics), publishing
//              a progress counter after each finalized chunk;
//   waves 1-7 = output: gather sorted values into registers early (latency
//              hidden under the sweep), spin on progress, masked store.
// Output thereby leaves the serial critical path.
__global__ __launch_bounds__(512) void mask_nms_out_kernel(unsigned char* __restrict__ ws,
                                                           float* __restrict__ out) {
    __shared__ unsigned long long av[128];                // final alive bits
    __shared__ int prog;                                  // sweep progress (chunks finalized)
    __shared__ int lastBlk;
    __shared__ union {
        struct { float cst[2][7][64];
                 unsigned long long cm[2][20], vm[2]; } m;   // mask staging + class masks
        struct { unsigned long long vd[128], supp[128];      // 2 KB
                 unsigned long long intra[128 * 64];         // 64 KB direct-mapped intra words
                 unsigned long long eword[CAP2];             // 32 KB packed cross words
                 unsigned short emeta[CAP2];                 // 8 KB  (row<<7)|target
                 unsigned int ccnt[128], offs[128];
                 unsigned int tot; } r;                      // ~107 KB resolve staging
    } u;

    int tid  = threadIdx.x;
    int lane = tid & 63;
    int wv   = tid >> 6;
    int blk  = blockIdx.x;                                // 256 blocks

    const float* sconf = (const float*)(ws + SB(4));
    const float* sx1 = (const float*)(ws + SB(6));
    const float* sy1 = (const float*)(ws + SB(7));
    const float* sx2 = (const float*)(ws + SB(8));
    const float* sy2 = (const float*)(ws + SB(9));
    const float* sar = (const float*)(ws + SB(10));
    const float* scl = (const float*)(ws + SB(5));

    // ---------------- phase 0: pre-zero invalid-rank output rows ----------------
    if (tid < 192) {
        int r = (blk << 5) + tid / 6;
        if (r < NBOX && !(sconf[r] > 0.5f))               // NaN/poison-safe negated test
            out[r * 6 + tid % 6] = 0.0f;
    }

    // ---------------- grid phase: tiles -> suppression-matrix words (verified r7/r8) ----------------
    {
    #pragma clang fp contract(off)
        int h  = tid >> 8;                       // half-block 0/1 (4 waves each)
        int tl = tid & 255;

        for (int k = 0; k < 8; ++k) {
            int t  = k * 512 + (blk << 1) + h;   // tile id in [0, 4096)
            int iy = t >> 7, w = t & 127;
            int i0 = iy << 8, j0 = w << 6;
            bool skip = (sconf[i0] <= 0.5f) || (sconf[j0] <= 0.5f) || (j0 + 64 <= i0);

            if (!skip && tl < 64) {              // full wave: stage cols + build masks
                int j = j0 + tl;
                float c0 = sx1[j], c1 = sy1[j], c2 = sx2[j], c3 = sy2[j];
                float c4 = sar[j], c5 = scl[j], c6 = sconf[j];
                u.m.cst[h][0][tl] = c0; u.m.cst[h][1][tl] = c1;
                u.m.cst[h][2][tl] = c2; u.m.cst[h][3][tl] = c3;
                u.m.cst[h][4][tl] = c4; u.m.cst[h][5][tl] = c5;
                u.m.cst[h][6][tl] = c6;
                unsigned long long vmk = __ballot(c6 > 0.5f);      // NaN-safe
                if (tl == 0) u.m.vm[h] = vmk;
                #pragma unroll
                for (int cl = 0; cl < 20; ++cl) {
                    unsigned long long mk = __ballot(c5 == (float)cl);
                    if (tl == 0) u.m.cm[h][cl] = mk;
                }
            }
            __syncthreads();

            if (!skip) {
                int i = i0 + tl;
                unsigned long long word = 0;
                if (sconf[i] > 0.5f && j0 + 64 > i + 1) {  // row i valid
                    float x1i = sx1[i], y1i = sy1[i], x2i = sx2[i], y2i = sy2[i];
                    float ai = sar[i], ci = scl[i];
                    int cii = (int)ci;
                    unsigned long long allowed = 0ull;
                    if (cii >= 0 && cii < 20)
                        allowed = u.m.cm[h][cii] & u.m.vm[h];
                    int d = i - j0 + 1;                    // first allowed col: j>i
                    unsigned long long gt =
                        (d <= 0) ? ~0ull : (d >= 64 ? 0ull : (~0ull << d));
                    unsigned long long it = allowed & gt;
                    while (it) {
                        int jj = __builtin_ctzll(it);
                        it &= it - 1ull;
                        float iw = fminf(x2i, u.m.cst[h][2][jj]) - fmaxf(x1i, u.m.cst[h][0][jj]);
                        iw = fmaxf(iw, 0.0f);
                        float ih = fminf(y2i, u.m.cst[h][3][jj]) - fmaxf(y1i, u.m.cst[h][1][jj]);
                        ih = fmaxf(ih, 0.0f);
                        float inter = iw * ih;
                        float denom = ai + u.m.cst[h][4][jj] - inter + 1e-6f;
                        if (inter / denom >= 0.5f) word |= (1ull << jj);
                    }
                }
                if (word) {                      // fire-and-forget; single writer per M word
                    int jc = j0 >> 6;
                    ((unsigned long long*)(ws + M_OFF))[(size_t)i * 128 + jc] = word;
                    atomicOr(((unsigned long long*)(ws + NZ_OFF)) + 2 * i + (jc >> 6),
                             1ull << (jc & 63));
                }
            }
            __syncthreads();
        }
    }

    // ---------------- completion: 2-level done tree (verified r7/r8) ----------------
    __threadfence();                              // release this block's M/nz writes
    if (tid == 0) {
        unsigned int* dc = (unsigned int*)(ws + DONE_OFF);
        lastBlk = 0;
        if (atomicAdd(dc + 1 + (blk & 7), 1u) == 31u)
            if (atomicAdd(dc, 1u) == 7u) lastBlk = 1;
    }
    __syncthreads();
    if (!lastBlk) return;
    __threadfence();                              // acquire: see all blocks' M/nz

    const unsigned long long* Mx = (const unsigned long long*)(ws + M_OFF);
    const ulonglong2* nzv = (const ulonglong2*)(ws + NZ_OFF);

    // ---------------- tail step 1: valid bitmap + zero resolve state ----------------
    for (int c = wv; c < 128; c += 8) {
        unsigned long long mk = __ballot(sconf[(c << 6) + lane] > 0.5f);
        if (lane == 0) u.r.vd[c] = mk;
    }
    for (int t = tid; t < 128 * 64; t += 512) u.r.intra[t] = 0ull;
    if (tid < 128) { u.r.supp[tid] = 0ull; av[tid] = 0ull; }
    if (tid == 0) prog = 0;
    __syncthreads();

    // ---------------- tail step 2a: counts + intra staging (nz cached in regs) ----------------
    unsigned long long nzx[16], nzy[16];
    #pragma unroll
    for (int q = 0; q < 16; ++q) {
        int c = (q << 3) + wv;                    // chunk handled by this wave
        int i = (c << 6) + lane;
        ulonglong2 nzp = nzv[i];                  // coalesced 16B/lane
        unsigned long long c0 = nzp.x, c1 = nzp.y;
        int cb = c & 63;
        if (c < 64) {
            if ((c0 >> cb) & 1ull) u.r.intra[(c << 6) + lane] = Mx[(size_t)i * 128 + c];
            c0 &= ~(1ull << cb);
        } else {
            if ((c1 >> cb) & 1ull) u.r.intra[(c << 6) + lane] = Mx[(size_t)i * 128 + c];
            c1 &= ~(1ull << cb);
        }
        nzx[q] = c0; nzy[q] = c1;
        int pc = __popcll(c0) + __popcll(c1);
        int scan = pc;
        #pragma unroll
        for (int d = 1; d < 64; d <<= 1) {
            int t = __shfl_up(scan, d, 64);
            if (lane >= d) scan += t;
        }
        if (lane == 63) u.r.ccnt[c] = (unsigned int)scan;
    }
    __syncthreads();

    // ---------------- tail step 2b: 128-entry exclusive scan (wave 0, verified) ----------------
    if (wv == 0) {
        unsigned int a0 = u.r.ccnt[2 * lane + 0];
        unsigned int a1 = u.r.ccnt[2 * lane + 1];
        unsigned int s = a0 + a1, incl = s;
        #pragma unroll
        for (int d = 1; d < 64; d <<= 1) {
            unsigned int t = __shfl_up(incl, d, 64);
            if (lane >= d) incl += t;
        }
        unsigned int excl = incl - s;
        u.r.offs[2 * lane + 0] = excl;  u.r.offs[2 * lane + 1] = excl + a0;
        if (lane == 63) u.r.tot = incl;
    }
    __syncthreads();
    bool fits = (u.r.tot <= (unsigned int)CAP2);

    // ---------------- tail step 2c: pack cross words into LDS (cached nz) ----------------
    if (fits) {
        #pragma unroll
        for (int q = 0; q < 16; ++q) {
            int c = (q << 3) + wv;
            int i = (c << 6) + lane;
            unsigned long long c0 = nzx[q], c1 = nzy[q];
            int pc = __popcll(c0) + __popcll(c1);
            int scan = pc;
            #pragma unroll
            for (int d = 1; d < 64; d <<= 1) {
                int t = __shfl_up(scan, d, 64);
                if (lane >= d) scan += t;
            }
            unsigned int o = u.r.offs[c] + (unsigned int)(scan - pc);
            while (c0) {
                int w = __builtin_ctzll(c0); c0 &= c0 - 1ull;
                u.r.emeta[o] = (unsigned short)((lane << 7) | w);
                u.r.eword[o] = Mx[(size_t)i * 128 + w];
                ++o;
            }
            while (c1) {
                int w = 64 + __builtin_ctzll(c1); c1 &= c1 - 1ull;
                u.r.emeta[o] = (unsigned short)((lane << 7) | w);
                u.r.eword[o] = Mx[(size_t)i * 128 + w];
                ++o;
            }
        }
    }
    __syncthreads();
    // ======== NO barriers beyond this point (waves diverge) ========

    if (wv == 0) {
        // ---------------- sweep (verified semantics) + progress publishing ----------------
        unsigned long long vdlo = u.r.vd[lane];          // vd in registers
        unsigned long long vdhi = u.r.vd[64 + lane];
        unsigned long long diag = u.r.intra[lane];       // prefetched chunk-0 state
        unsigned int cnt  = u.r.ccnt[0];
        unsigned int base = u.r.offs[0];

        int jc = 0;
        for (; jc < 128; ++jc) {
            unsigned long long vsrc = (jc < 64) ? vdlo : vdhi;
            unsigned int vlo = (unsigned int)__builtin_amdgcn_readlane((int)(unsigned int)vsrc, jc & 63);
            unsigned int vhi = (unsigned int)__builtin_amdgcn_readlane((int)(unsigned int)(vsrc >> 32), jc & 63);
            unsigned long long v = ((unsigned long long)vhi << 32) | (unsigned long long)vlo;
            if (v == 0ull) break;                 // sorted: no valid boxes beyond

            unsigned long long sj = u.r.supp[jc]; // pushes into jc already drained
            unsigned long long a = v & ~sj;

            // prefetch next chunk's state while resolving this one
            unsigned long long diagN = (jc < 127) ? u.r.intra[((jc + 1) << 6) + lane] : 0ull;
            unsigned int cntN  = (jc < 127) ? u.r.ccnt[jc + 1] : 0u;
            unsigned int baseN = (jc < 127) ? u.r.offs[jc + 1] : 0u;

            // intra-chunk: ascending scan over rows with intra bits (bits j>i only)
            unsigned long long scan = __ballot(diag != 0ull) & a;
            while (scan) {
                int ib = __builtin_ctzll(scan);
                scan &= scan - 1ull;
                if ((a >> ib) & 1ull) {
                    unsigned int dlo = (unsigned int)__builtin_amdgcn_readlane((int)(unsigned int)diag, ib);
                    unsigned int dhi = (unsigned int)__builtin_amdgcn_readlane((int)(unsigned int)(diag >> 32), ib);
                    a &= ~(((unsigned long long)dhi << 32) | (unsigned long long)dlo);
                }
            }
            if (lane == 0) av[jc] = a;

            if (fits) {
                // push packed cross words of alive rows (LDS only)
                for (unsigned int e0 = 0; e0 < cnt; e0 += 64) {
                    unsigned int e = e0 + lane;
                    if (e < cnt) {
                        unsigned int m = u.r.emeta[base + e];
                        if ((a >> (m >> 7)) & 1ull)
                            atomicOr(&u.r.supp[m & 127], u.r.eword[base + e]);
                    }
                }
            } else {
                // fallback: push from global M (verified r7 path; overflow only)
                int i = (jc << 6) + lane;
                ulonglong2 nzp = nzv[i];
                unsigned long long c0 = nzp.x, c1 = nzp.y;
                if (jc < 64) c0 &= ~(1ull << jc); else c1 &= ~(1ull << (jc & 63));
                if ((a >> lane) & 1ull) {
                    while (c0) {
                        int w = __builtin_ctzll(c0); c0 &= c0 - 1ull;
                        atomicOr(&u.r.supp[w], Mx[(size_t)i * 128 + w]);
                    }
                    while (c1) {
                        int w = __builtin_ctzll(c1); c1 &= c1 - 1ull;
                        atomicOr(&u.r.supp[64 + w], Mx[(size_t)i * 128 + 64 + w]);
                    }
                }
                asm volatile("s_waitcnt vmcnt(0)" ::: "memory");
            }
            asm volatile("s_waitcnt lgkmcnt(0)" ::: "memory");  // pushes + av store visible
            __builtin_amdgcn_sched_barrier(0);
            if (lane == 0) *(volatile int*)&prog = jc + 1;      // publish
            diag = diagN; cnt = cntN; base = baseN;
        }
        __threadfence_block();
        if (lane == 0) *(volatile int*)&prog = 128;             // av[jc..] stay 0
    } else {
        // ---------------- output: waves 1-7, pipelined behind the sweep ----------------
        const float* s0 = (const float*)(ws + SB(0));
        const float* s1 = (const float*)(ws + SB(1));
        const float* s2 = (const float*)(ws + SB(2));
        const float* s3 = (const float*)(ws + SB(3));
        const float* s4 = (const float*)(ws + SB(4));
        const float* s5 = (const float*)(ws + SB(5));

        for (int c = wv - 1; c < 16; c += 7) {
            if (!(sconf[c << 9] > 0.5f)) continue;   // chunk fully invalid: pre-zeroed
            float g[8][6];
            #pragma unroll
            for (int k = 0; k < 8; ++k) {            // issue gathers early (latency hidden)
                int r = (c << 9) + (k << 6) + lane;
                bool ok = (r < NBOX);
                g[k][0] = ok ? s0[r] : 0.f;  g[k][1] = ok ? s1[r] : 0.f;
                g[k][2] = ok ? s2[r] : 0.f;  g[k][3] = ok ? s3[r] : 0.f;
                g[k][4] = ok ? s4[r] : 0.f;  g[k][5] = ok ? s5[r] : 0.f;
            }
            int target = (c << 3) + 8;               // av words needed: [c*8, c*8+8)
            while (*(volatile int*)&prog < target) { }
            __threadfence_block();                   // acquire av written before prog
            #pragma unroll
            for (int k = 0; k < 8; ++k) {
                int r = (c << 9) + (k << 6) + lane;
                if (r >= NBOX) continue;
                bool keep = (av[(c << 3) + k] >> lane) & 1ull;
                out[r * 6 + 0] = keep ? g[k][0] : 0.f;
                out[r * 6 + 1] = keep ? g[k][1] : 0.f;
                out[r * 6 + 2] = keep ? g[k][2] : 0.f;
                out[r * 6 + 3] = keep ? g[k][3] : 0.f;
                out[r * 6 + 4] = keep ? g[k][4] : 0.f;
                out[r * 6 + 5] = keep ? g[k][5] : 0.f;
            }
        }
    }
}

extern "C" void kernel_launch(void* const* d_in, const int* in_sizes, int n_in,
                              void* d_out, int out_size, void* d_ws, size_t ws_size,
                              hipStream_t stream) {
    const float* x       = (const float*)d_in[0];
    const float* anchors = (const float*)d_in[1];
    float* out           = (float*)d_out;
    unsigned char* ws    = (unsigned char*)d_ws;

    sort_decode_kernel<<<256, 512, 0, stream>>>(x, anchors, ws);
    mask_nms_out_kernel<<<256, 512, 0, stream>>>(ws, out);
}